// Round 8
// baseline (331.570 us; speedup 1.0000x reference)
//
#include <hip/hip_runtime.h>
#include <hip/hip_bf16.h>

// NestedAttention: B=16,N=1024,D=1024,E=4,H=16,hd=64
// bf16 MFMA pipeline with fp32 accumulate.
// R8: GEMMs back to the m97 128x128 / 4-wave / 32KB-LDS structure (4
// blocks/CU -> inter-block overlap hides stage drains; R7's 256^2 ran 1
// block/CU, latency-bound at 14% occupancy) + T2 swizzle (R2's 3.8e7 bank
// conflicts -> 0) + finer nested-K granularity (E[NT] 9.3 -> 7.5) + LPT
// block order (heavy experts first) + XCD chunking.
// Pipeline: per-batch expert sort; everything runs in permuted token space.

typedef __bf16 bf16_t;
typedef __bf16 bf16x8 __attribute__((ext_vector_type(8)));
typedef __bf16 bf16x4 __attribute__((ext_vector_type(4)));
typedef float f32x4 __attribute__((ext_vector_type(4)));
typedef float f32x16 __attribute__((ext_vector_type(16)));
typedef int i32x4 __attribute__((ext_vector_type(4)));

typedef __attribute__((address_space(1))) void gvoid;
typedef __attribute__((address_space(3))) void lvoid;

#define MFMA16(a, b, c) __builtin_amdgcn_mfma_f32_16x16x32_bf16((a), (b), (c), 0, 0, 0)
#define MFMA32(a, b, c) __builtin_amdgcn_mfma_f32_32x32x16_bf16((a), (b), (c), 0, 0, 0)
#define GLOAD_LDS16(gsrc, ldst) \
  __builtin_amdgcn_global_load_lds((gvoid*)(gsrc), (lvoid*)(ldst), 16, 0, 0)

// softmax scale 1/sqrt(64) folded with log2(e) into Q at QKV epilogue
#define QSCALE 0.18033688f

__device__ __forceinline__ unsigned cvtpk(float lo, float hi) {
  unsigned r;
  asm("v_cvt_pk_bf16_f32 %0, %1, %2" : "=v"(r) : "v"(lo), "v"(hi));
  return r;
}
__device__ __forceinline__ void pl32swap(unsigned& x, unsigned& y) {
  asm("v_permlane32_swap_b32 %0, %1" : "+v"(x), "+v"(y));
}

// ------------------------------------------------------------- sorting ----
// Per-batch counting sort (16 batches x 1024 tokens) into ascending-expert
// order. perm[b*1024+np] = original n; ems[b*1024+np] = expert. Bucket
// boundaries are deterministic (counts); within-bucket order is atomic-race
// dependent, but every output row depends only on its own token, so final
// outputs are bit-identical across replays.
__global__ __launch_bounds__(256) void sort_batch(
    const int* __restrict__ em, int* __restrict__ perm, int* __restrict__ ems) {
  __shared__ int cnt[4], base[4], cur[4];
  const int b = blockIdx.x, t = threadIdx.x;
  if (t < 4) cnt[t] = 0;
  __syncthreads();
  int e[4];
#pragma unroll
  for (int i = 0; i < 4; ++i) {
    e[i] = em[b * 1024 + t * 4 + i];
    atomicAdd(&cnt[e[i]], 1);
  }
  __syncthreads();
  if (t == 0) {
    base[0] = 0; base[1] = cnt[0];
    base[2] = cnt[0] + cnt[1]; base[3] = cnt[0] + cnt[1] + cnt[2];
    cur[0] = cur[1] = cur[2] = cur[3] = 0;
  }
  __syncthreads();
#pragma unroll
  for (int i = 0; i < 4; ++i) {
    const int pos = base[e[i]] + atomicAdd(&cur[e[i]], 1);
    perm[b * 1024 + pos] = t * 4 + i;
    ems[b * 1024 + pos] = e[i];
  }
}

// ---------------------------------------------------------------- prep ----
// gather token perm[np] of batch b -> permuted row np (coalesced 4KB row
// reads, contiguous writes), masked+converted to bf16.
__global__ __launch_bounds__(256) void prep_tokens(
    const float* __restrict__ x, const int* __restrict__ perm,
    const int* __restrict__ ems, bf16_t* __restrict__ xq) {
  const int prow = blockIdx.x;                // permuted row 0..16383
  const int orig = (prow & ~1023) + perm[prow];
  const int dt = 128 << ems[prow];            // token's nested dim
  const int d = threadIdx.x * 4;
  float4 v = ((const float4*)(x + (size_t)orig * 1024))[threadIdx.x];
  const bool keep = d < dt;                   // dt multiple of 128 -> uniform per 4
  bf16x4 o;
  o[0] = (bf16_t)(keep ? v.x : 0.f);
  o[1] = (bf16_t)(keep ? v.y : 0.f);
  o[2] = (bf16_t)(keep ? v.z : 0.f);
  o[3] = (bf16_t)(keep ? v.w : 0.f);
  *((bf16x4*)(xq + (size_t)prow * 1024 + d)) = o;
}

__global__ __launch_bounds__(256) void conv_w(
    const float* __restrict__ s, bf16_t* __restrict__ dvec) {
  const int i = blockIdx.x * 256 + threadIdx.x;  // grid sized exactly, no guard
  float4 v = ((const float4*)s)[i];
  bf16x4 o;
  o[0] = (bf16_t)v.x; o[1] = (bf16_t)v.y; o[2] = (bf16_t)v.z; o[3] = (bf16_t)v.w;
  ((bf16x4*)dvec)[i] = o;
}

// ---------------------------------------------------------------- GEMM ----
// C[m,f] = sum_k A[m,k] * Bw[f,k]  ("B^T" GEMM) over PERMUTED-space rows.
// m97 structure: 128x128 tile, BK=64, 4 waves, single-buffered 32KB LDS,
// 2 barriers/K-tile, 4 blocks/CU (launch_bounds(256,4)) -> inter-block
// overlap hides the vmcnt(0) drains. T2 chunk-swizzle on LDS (inverse-
// swizzled global source + swizzled ds_read; rule #21).
// Block map: bijective XCD chunks; within a chunk, col-major panels (B
// L2-reuse) with LPT row order (heavy experts first within each batch).
// EPI 0 (QKV): K-loop to block's max nested dim (ascending experts; zeros
//   beyond a row's own dt keep straddle blocks exact). Writes q/k/vT at
//   PERMUTED positions.
// EPI 1 (proj): full K; blocks with colbase >= dtmax write zero rows and
//   exit; else per-row mask; rows scattered to original token positions.
template <int EPI>
__global__ __launch_bounds__(256, 4) void gemm128(
    const bf16_t* __restrict__ A, const bf16_t* __restrict__ Bw, int K,
    const int* __restrict__ perm, const int* __restrict__ ems,
    bf16_t* __restrict__ qo, bf16_t* __restrict__ ko, bf16_t* __restrict__ vto,
    float* __restrict__ yout, const float* __restrict__ bias) {
  __shared__ bf16_t As[128 * 64];
  __shared__ bf16_t Bs[128 * 64];
  const int tid = threadIdx.x;
  const int lane = tid & 63, w = tid >> 6;
  const int g = lane >> 4, c16 = lane & 15;
  const int wr = (w >> 1) * 64, wc = (w & 1) * 64;

  // bijective XCD chunking; within chunk: col changes every 128 lb (B-panel
  // stays L2-resident), row-blocks LPT-ordered (descending expert in batch).
  const int nwg = gridDim.x;
  const int lb = ((int)blockIdx.x & 7) * (nwg >> 3) + ((int)blockIdx.x >> 3);
  const int rr = lb & 127;
  const int rowblk = (rr & ~7) | (7 - (rr & 7));  // heavy-first within batch
  const int rowbase = rowblk * 128;
  const int colbase = (lb >> 7) * 128;

  // block's max nested dim (128 | 1024 -> never straddles batches; rows
  // ascending by expert within batch -> last row has the max)
  const int dtmax = 128 << ems[rowbase + 127];

  if constexpr (EPI == 1) {
    if (colbase >= dtmax) {  // whole block masked -> write zero rows, done
      const float4 z = make_float4(0.f, 0.f, 0.f, 0.f);
#pragma unroll
      for (int i = 0; i < 8; ++i) {
        const int idx = i * 256 + tid;
        const int r = idx >> 5, c4 = idx & 31;
        const int orow = ((rowbase + r) & ~1023) + perm[rowbase + r];
        ((float4*)(yout + (size_t)orow * 1024 + colbase))[c4] = z;
      }
      return;
    }
  }

  const int NT = (EPI == 0) ? (dtmax >> 6) : (K >> 6);  // nested K for QKV

  // staging: thread stages 4 chunks of 16B per matrix per K-tile; linear LDS
  // dest (global_load_lds), inverse-swizzled global k-chunk col.
  const int scol = (((tid & 7) ^ ((tid >> 3) & 7)) << 3);
  const bf16_t* pa = A + (size_t)(rowbase + (tid >> 3)) * K + scol;
  const bf16_t* pb = Bw + (size_t)(colbase + (tid >> 3)) * K + scol;

  f32x4 acc[4][4] = {};

  for (int t = 0; t < NT; ++t) {
    const int kt = t << 6;
#pragma unroll
    for (int ch = 0; ch < 4; ++ch) {
      GLOAD_LDS16(pa + (size_t)(ch * 32) * K + kt, As + (ch * 256 + w * 64) * 8);
      GLOAD_LDS16(pb + (size_t)(ch * 32) * K + kt, Bs + (ch * 256 + w * 64) * 8);
    }
    asm volatile("s_waitcnt vmcnt(0)" ::: "memory");
    __syncthreads();
#pragma unroll
    for (int kk = 0; kk < 2; ++kk) {
      bf16x8 af[4], bfr[4];
#pragma unroll
      for (int mi = 0; mi < 4; ++mi)
        af[mi] = *(const bf16x8*)(As + (wr + mi * 16 + c16) * 64 +
                                  ((((kk << 2) + g) ^ (c16 & 7)) << 3));
#pragma unroll
      for (int ni = 0; ni < 4; ++ni)
        bfr[ni] = *(const bf16x8*)(Bs + (wc + ni * 16 + c16) * 64 +
                                   ((((kk << 2) + g) ^ (c16 & 7)) << 3));
#pragma unroll
      for (int mi = 0; mi < 4; ++mi)
#pragma unroll
        for (int ni = 0; ni < 4; ++ni)
          acc[mi][ni] = MFMA16(af[mi], bfr[ni], acc[mi][ni]);
    }
    __syncthreads();
  }

  // C/D layout: col = lane&15, row = (lane>>4)*4 + reg  [m89/m91 verified]
  if constexpr (EPI == 0) {
    const int s = colbase >> 10;  // 0=q,1=k,2=v (uniform per block: 128|1024)
#pragma unroll
    for (int mi = 0; mi < 4; ++mi)
#pragma unroll
      for (int j = 0; j < 4; ++j) {
        const int row = rowbase + wr + mi * 16 + g * 4 + j;  // permuted row
        const int bb = row >> 10, n = row & 1023;  // n = permuted position
#pragma unroll
        for (int ni = 0; ni < 4; ++ni) {
          const int col = colbase + wc + ni * 16 + c16;  // f
          const float v = acc[mi][ni][j];
          const int h = (col >> 6) & 15, e = col & 63;
          const size_t bh = (size_t)(bb * 16 + h);
          if (s == 0)
            qo[(bh * 1024 + n) * 64 + e] = (bf16_t)(v * QSCALE);
          else if (s == 1)
            ko[(bh * 1024 + n) * 64 + e] = (bf16_t)v;
          else
            vto[(bh * 64 + e) * 1024 + n] = (bf16_t)v;  // V transposed
        }
      }
  } else {
#pragma unroll
    for (int mi = 0; mi < 4; ++mi)
#pragma unroll
      for (int j = 0; j < 4; ++j) {
        const int row = rowbase + wr + mi * 16 + g * 4 + j;  // permuted
        const int dt = 128 << ems[row];
        const int orow = (row & ~1023) + perm[row];  // original token row
#pragma unroll
        for (int ni = 0; ni < 4; ++ni) {
          const int col = colbase + wc + ni * 16 + c16;
          const float v = acc[mi][ni][j] + bias[col];
          yout[(size_t)orow * 1024 + col] = (col < dt) ? v : 0.f;
        }
      }
  }
}

// ----------------------------------------------------------- attention ----
// Runs entirely in permuted token space (softmax over a batch's keys is
// permutation-invariant; each output row is its own query's result).
// 8 waves x 32 q-rows = 256 q rows / block. KVBLK=64 double-buffered in LDS
// (K row-major [64key][64d], V^T [64d][64key], both XOR-swizzled).
// Swapped QK^T: S = mfma32(Kfrag, Qfrag) -> lane holds P-row slice for
// q = lane&31 in registers; softmax fully in-register; P->bf16 via
// cvt_pk + permlane32_swap feeds PV's A operand directly.
__global__ __launch_bounds__(512, 2) void attn256(
    const bf16_t* __restrict__ Q, const bf16_t* __restrict__ Kb,
    const bf16_t* __restrict__ VT, bf16_t* __restrict__ X) {
  __shared__ bf16_t Klds[2][4096];
  __shared__ bf16_t Vlds[2][4096];
  const int tid = threadIdx.x;
  const int w = tid >> 6, lane = tid & 63;
  const int k32 = lane & 31, q5 = lane >> 5;
  const int bh = blockIdx.y;
  const int qbase = blockIdx.x * 256 + w * 32;

  const bf16_t* Qbh = Q + (size_t)bh * 65536;
  const bf16_t* Kbh = Kb + (size_t)bh * 65536;
  const bf16_t* Vbh = VT + (size_t)bh * 65536;

  const int trow = tid >> 3;
  const int tslot = (tid & 7) ^ (trow & 7);
  const bf16_t* kg = Kbh + (size_t)trow * 64 + tslot * 8;
  const bf16_t* vg = Vbh + (size_t)trow * 1024 + tslot * 8;

  bf16x8 qf[4];
#pragma unroll
  for (int kc = 0; kc < 4; ++kc)
    qf[kc] = *(const bf16x8*)(Qbh + (size_t)(qbase + k32) * 64 + kc * 16 + q5 * 8);
  asm volatile("" ::"v"(qf[0]), "v"(qf[1]), "v"(qf[2]), "v"(qf[3]));

  const int rbase = k32 * 128 + q5 * 16;
  const int rswz = (k32 & 7) << 4;

  f32x16 O0 = {}, O1 = {};
  float m = -3.0e38f, lsum = 0.f;

  GLOAD_LDS16(kg, (bf16_t*)Klds[0] + tid * 8);
  GLOAD_LDS16(vg, (bf16_t*)Vlds[0] + tid * 8);

  for (int step = 0; step < 16; ++step) {
    const int buf = step & 1;
    if (step < 15) {
      GLOAD_LDS16(kg + (step + 1) * 4096, (bf16_t*)Klds[buf ^ 1] + tid * 8);
      GLOAD_LDS16(vg + (step + 1) * 64, (bf16_t*)Vlds[buf ^ 1] + tid * 8);
      asm volatile("s_waitcnt vmcnt(2)" ::: "memory");
    } else {
      asm volatile("s_waitcnt vmcnt(0)" ::: "memory");
    }
    __builtin_amdgcn_s_barrier();

    const char* Kl = (const char*)Klds[buf];
    const char* Vl = (const char*)Vlds[buf];

    f32x16 S0 = {}, S1 = {};
#pragma unroll
    for (int kc = 0; kc < 4; ++kc) {
      const int off = (rbase + kc * 32) ^ rswz;
      bf16x8 kf0 = *(const bf16x8*)(Kl + off);
      bf16x8 kf1 = *(const bf16x8*)(Kl + off + 4096);
      S0 = MFMA32(kf0, qf[kc], S0);
      S1 = MFMA32(kf1, qf[kc], S1);
    }

    float pm = fmaxf(S0[0], S1[0]);
#pragma unroll
    for (int r = 1; r < 16; ++r) pm = fmaxf(pm, fmaxf(S0[r], S1[r]));
    pm = fmaxf(pm, __shfl_xor(pm, 32));
    if (__any(pm > m + 8.f)) {           // defer-max, THR=8 (log2 domain)
      const float mnew = fmaxf(m, pm);
      const float corr = __builtin_amdgcn_exp2f(m - mnew);
      m = mnew;
      lsum *= corr;
      const int ci = __builtin_bit_cast(int, corr);
#pragma unroll
      for (int r = 0; r < 16; ++r) {
        const int qsel = (r & 3) + 8 * (r >> 2) + 4 * q5;
        const float cr = __builtin_bit_cast(
            float, __builtin_amdgcn_ds_bpermute(qsel << 2, ci));
        O0[r] *= cr;
        O1[r] *= cr;
      }
    }
    float ps = 0.f;
#pragma unroll
    for (int r = 0; r < 16; ++r) {
      float p = __builtin_amdgcn_exp2f(S0[r] - m);
      ps += p; S0[r] = p;
      p = __builtin_amdgcn_exp2f(S1[r] - m);
      ps += p; S1[r] = p;
    }
    lsum += ps;

#define MAKE_PA(PV, B0, PA)                            \
  {                                                    \
    unsigned a_ = cvtpk(PV[B0 + 0], PV[B0 + 1]);       \
    unsigned b_ = cvtpk(PV[B0 + 2], PV[B0 + 3]);       \
    unsigned c_ = cvtpk(PV[B0 + 4], PV[B0 + 5]);       \
    unsigned d_ = cvtpk(PV[B0 + 6], PV[B0 + 7]);       \
    pl32swap(a_, c_);                                  \
    pl32swap(b_, d_);                                  \
    i32x4 wv_;                                         \
    wv_[0] = a_; wv_[1] = b_; wv_[2] = c_; wv_[3] = d_; \
    PA = __builtin_bit_cast(bf16x8, wv_);              \
  }
#define PV_STEP(PV, B0, KS)                                       \
  {                                                               \
    bf16x8 pa;                                                    \
    MAKE_PA(PV, B0, pa);                                          \
    const int voff = (rbase + (KS) * 32) ^ rswz;                  \
    bf16x8 vf0 = *(const bf16x8*)(Vl + voff);                     \
    bf16x8 vf1 = *(const bf16x8*)(Vl + voff + 4096);              \
    O0 = MFMA32(pa, vf0, O0);                                     \
    O1 = MFMA32(pa, vf1, O1);                                     \
  }
    PV_STEP(S0, 0, 0)
    PV_STEP(S0, 8, 1)
    PV_STEP(S1, 0, 2)
    PV_STEP(S1, 8, 3)

    __builtin_amdgcn_s_barrier();
  }

  lsum += __shfl_xor(lsum, 32);
  const float rinv = 1.f / lsum;
  const int ri = __builtin_bit_cast(int, rinv);
  const int bb = bh >> 4, h = bh & 15;
  bf16_t* Xb = X + (size_t)bb * 1024 * 1024 + h * 64;
#pragma unroll
  for (int r = 0; r < 16; ++r) {
    const int qsel = (r & 3) + 8 * (r >> 2) + 4 * q5;
    const float rv = __builtin_bit_cast(
        float, __builtin_amdgcn_ds_bpermute(qsel << 2, ri));
    const size_t rowoff = (size_t)(qbase + qsel) * 1024;
    Xb[rowoff + k32] = (bf16_t)(O0[r] * rv);
    Xb[rowoff + 32 + k32] = (bf16_t)(O1[r] * rv);
  }
}

// --------------------------------------------------------------- launch ----
extern "C" void kernel_launch(void* const* d_in, const int* in_sizes, int n_in,
                              void* d_out, int out_size, void* d_ws,
                              size_t ws_size, hipStream_t stream) {
  const float* x = (const float*)d_in[0];
  const int* em = (const int*)d_in[1];
  const float* qkvw = (const float*)d_in[2];
  const float* projw = (const float*)d_in[3];
  const float* projb = (const float*)d_in[4];
  float* out = (float*)d_out;

  char* ws = (char*)d_ws;
  size_t off = 0;
  bf16_t* xin = (bf16_t*)(ws + off); off += (size_t)16384 * 1024 * 2;  // reused as Xattn
  bf16_t* wq  = (bf16_t*)(ws + off); off += (size_t)3072 * 1024 * 2;
  bf16_t* wp  = (bf16_t*)(ws + off); off += (size_t)1024 * 1024 * 2;
  bf16_t* Qb  = (bf16_t*)(ws + off); off += (size_t)256 * 1024 * 64 * 2;
  bf16_t* Kb  = (bf16_t*)(ws + off); off += (size_t)256 * 1024 * 64 * 2;
  bf16_t* VTb = (bf16_t*)(ws + off); off += (size_t)256 * 64 * 1024 * 2;
  int* perm   = (int*)(ws + off); off += 16384 * 4;   // perm[b*1024+np] = n
  int* ems    = (int*)(ws + off); off += 16384 * 4;   // expert of sorted slot

  // per-batch counting sort (deterministic bucket structure)
  sort_batch<<<16, 256, 0, stream>>>(em, perm, ems);

  // gather tokens into permuted order + mask + bf16
  prep_tokens<<<16384, 256, 0, stream>>>(x, perm, ems, xin);
  conv_w<<<3072, 256, 0, stream>>>(qkvw, wq);
  conv_w<<<1024, 256, 0, stream>>>(projw, wp);

  // QKV: M=16384 (permuted, nested-K), N=3072 -> 128x24 = 3072 blocks
  gemm128<0><<<3072, 256, 0, stream>>>(
      xin, wq, 1024, perm, ems, Qb, Kb, VTb, nullptr, nullptr);

  // attention in permuted space: 4 q-tiles x 256 (b,h); X -> xin region
  attn256<<<dim3(4, 256), 512, 0, stream>>>(Qb, Kb, VTb, xin);

  // proj: M=16384 (permuted), N=1024, masked-block skip -> 128x8 = 1024
  gemm128<1><<<1024, 256, 0, stream>>>(
      xin, wp, 1024, perm, ems, nullptr, nullptr, nullptr, out, projb);
}